// Round 1
// baseline (983.305 us; speedup 1.0000x reference)
//
#include <hip/hip_runtime.h>

#define EPS 1e-3f

// ---------------------------------------------------------------------------
// Kernel A: center-tap GEMM  out[n][col] = feats[n] . W13[:,col] + bias[col]
// tile 128 rows x 128 cols, 256 threads, 8x8 register tile per thread.
// LDS: feats 128x64 (stride 65, conflict-free broadcast reads) = 33280 B
//      W slice 32x128 (restaged twice)                         = 16384 B
// ---------------------------------------------------------------------------
__global__ __launch_bounds__(256) void center_gemm(
    const float* __restrict__ f1, const float* __restrict__ f2,
    const float* __restrict__ W, const float* __restrict__ bias,
    float* __restrict__ out, int N, int N1) {
  __shared__ float fLDS[128 * 65];
  __shared__ float wLDS[32 * 128];
  const int tid = threadIdx.x;
  const int tx = tid & 15, ty = tid >> 4;
  const int row0 = blockIdx.x * 128;

  // stage feats tile: 128 rows x 64 c (float4 global loads, scalar LDS writes)
  for (int k = 0; k < 8; ++k) {
    int flat4 = tid + k * 256;          // 0..2047
    int row = flat4 >> 4, c4 = flat4 & 15;
    int grow = row0 + row;
    float4 v = make_float4(0.f, 0.f, 0.f, 0.f);
    if (grow < N) {
      const float* src = (grow < N1) ? (f1 + (size_t)grow * 64)
                                     : (f2 + (size_t)(grow - N1) * 64);
      v = *(const float4*)(src + c4 * 4);
    }
    int l = row * 65 + c4 * 4;
    fLDS[l + 0] = v.x; fLDS[l + 1] = v.y; fLDS[l + 2] = v.z; fLDS[l + 3] = v.w;
  }

  float acc[8][8];
#pragma unroll
  for (int r = 0; r < 8; ++r)
#pragma unroll
    for (int j = 0; j < 8; ++j) acc[r][j] = 0.f;

  for (int kk = 0; kk < 64; kk += 32) {
    __syncthreads();
    // stage W rows kk..kk+31
    for (int k = 0; k < 4; ++k) {
      int flat4 = tid + k * 256;        // 0..1023
      int c = flat4 >> 5, col4 = flat4 & 31;
      float4 v = *(const float4*)(W + (size_t)(kk + c) * 128 + col4 * 4);
      *(float4*)(wLDS + c * 128 + col4 * 4) = v;
    }
    __syncthreads();

#pragma unroll 4
    for (int c = 0; c < 32; ++c) {
      float a[8];
#pragma unroll
      for (int r = 0; r < 8; ++r) a[r] = fLDS[(ty * 8 + r) * 65 + kk + c];
      float4 b0 = *(const float4*)(wLDS + c * 128 + tx * 8);
      float4 b1 = *(const float4*)(wLDS + c * 128 + tx * 8 + 4);
      float b[8] = {b0.x, b0.y, b0.z, b0.w, b1.x, b1.y, b1.z, b1.w};
#pragma unroll
      for (int r = 0; r < 8; ++r)
#pragma unroll
        for (int j = 0; j < 8; ++j) acc[r][j] += a[r] * b[j];
    }
  }

  float4 bi0 = *(const float4*)(bias + tx * 8);
  float4 bi1 = *(const float4*)(bias + tx * 8 + 4);
#pragma unroll
  for (int r = 0; r < 8; ++r) {
    int grow = row0 + ty * 8 + r;
    if (grow < N) {
      float4 o0 = make_float4(acc[r][0] + bi0.x, acc[r][1] + bi0.y,
                              acc[r][2] + bi0.z, acc[r][3] + bi0.w);
      float4 o1 = make_float4(acc[r][4] + bi1.x, acc[r][5] + bi1.y,
                              acc[r][6] + bi1.z, acc[r][7] + bi1.w);
      float* dst = out + (size_t)grow * 128 + tx * 8;
      *(float4*)dst = o0;
      *(float4*)(dst + 4) = o1;
    }
  }
}

// ---------------------------------------------------------------------------
// Kernel B: 26 neighbor taps. Same GEMM tiling; rows gathered, epilogue
// scatter-adds with atomics (rows unique within a tap, collide across taps).
// Padding entries have gather==scatter==N and sit at the tail of each tap.
// ---------------------------------------------------------------------------
__global__ __launch_bounds__(256) void msg_gemm(
    const float* __restrict__ f1, const float* __restrict__ f2,
    const float* __restrict__ W27, const int* __restrict__ G,
    const int* __restrict__ S, float* __restrict__ out,
    int N, int N1, int pm) {
  const int i = blockIdx.y;
  const int ktap = i + (i >= 13 ? 1 : 0);
  const float* W = W27 + (size_t)ktap * 64 * 128;
  const int* Gi = G + (size_t)i * pm;
  const int* Si = S + (size_t)i * pm;
  const int p0 = blockIdx.x * 128;

  // fully-padded block: padding is at the tail, so check first entry
  if (Si[p0] >= N) return;

  __shared__ float fLDS[128 * 65];
  __shared__ float wLDS[32 * 128];
  const int tid = threadIdx.x;
  const int tx = tid & 15, ty = tid >> 4;

  for (int k = 0; k < 8; ++k) {
    int flat4 = tid + k * 256;
    int row = flat4 >> 4, c4 = flat4 & 15;
    int p = p0 + row;
    float4 v = make_float4(0.f, 0.f, 0.f, 0.f);
    if (p < pm) {
      int g = Gi[p];
      if (g < N) {
        const float* src = (g < N1) ? (f1 + (size_t)g * 64)
                                    : (f2 + (size_t)(g - N1) * 64);
        v = *(const float4*)(src + c4 * 4);
      }
    }
    int l = row * 65 + c4 * 4;
    fLDS[l + 0] = v.x; fLDS[l + 1] = v.y; fLDS[l + 2] = v.z; fLDS[l + 3] = v.w;
  }

  float acc[8][8];
#pragma unroll
  for (int r = 0; r < 8; ++r)
#pragma unroll
    for (int j = 0; j < 8; ++j) acc[r][j] = 0.f;

  for (int kk = 0; kk < 64; kk += 32) {
    __syncthreads();
    for (int k = 0; k < 4; ++k) {
      int flat4 = tid + k * 256;
      int c = flat4 >> 5, col4 = flat4 & 31;
      float4 v = *(const float4*)(W + (size_t)(kk + c) * 128 + col4 * 4);
      *(float4*)(wLDS + c * 128 + col4 * 4) = v;
    }
    __syncthreads();

#pragma unroll 4
    for (int c = 0; c < 32; ++c) {
      float a[8];
#pragma unroll
      for (int r = 0; r < 8; ++r) a[r] = fLDS[(ty * 8 + r) * 65 + kk + c];
      float4 b0 = *(const float4*)(wLDS + c * 128 + tx * 8);
      float4 b1 = *(const float4*)(wLDS + c * 128 + tx * 8 + 4);
      float b[8] = {b0.x, b0.y, b0.z, b0.w, b1.x, b1.y, b1.z, b1.w};
#pragma unroll
      for (int r = 0; r < 8; ++r)
#pragma unroll
        for (int j = 0; j < 8; ++j) acc[r][j] += a[r] * b[j];
    }
  }

#pragma unroll
  for (int r = 0; r < 8; ++r) {
    int p = p0 + ty * 8 + r;
    if (p < pm) {
      int s = Si[p];
      if (s < N) {
        float* dst = out + (size_t)s * 128 + tx * 8;
#pragma unroll
        for (int j = 0; j < 8; ++j) unsafeAtomicAdd(dst + j, acc[r][j]);
      }
    }
  }
}

// ---------------------------------------------------------------------------
// Kernel C: per-channel sum and sum-of-squares into ws[0..127], ws[128..255]
// ---------------------------------------------------------------------------
__global__ __launch_bounds__(256) void stats_kernel(
    const float* __restrict__ out, float* __restrict__ ws, int total4) {
  const int tid = threadIdx.x;
  float4 s = make_float4(0.f, 0.f, 0.f, 0.f);
  float4 q = make_float4(0.f, 0.f, 0.f, 0.f);
  const float4* o4 = (const float4*)out;
  for (int idx = blockIdx.x * 256 + tid; idx < total4; idx += gridDim.x * 256) {
    float4 v = o4[idx];
    s.x += v.x; s.y += v.y; s.z += v.z; s.w += v.w;
    q.x += v.x * v.x; q.y += v.y * v.y; q.z += v.z * v.z; q.w += v.w * v.w;
  }
  __shared__ float red[8 * 32 * 8];
  const int col4 = tid & 31, grp = tid >> 5;
  float* my = red + (grp * 32 + col4) * 8;
  my[0] = s.x; my[1] = s.y; my[2] = s.z; my[3] = s.w;
  my[4] = q.x; my[5] = q.y; my[6] = q.z; my[7] = q.w;
  __syncthreads();
  {
    int c4 = tid & 31, j = tid >> 5;   // j in 0..7
    float v = 0.f;
#pragma unroll
    for (int g = 0; g < 8; ++g) v += red[(g * 32 + c4) * 8 + j];
    int col = c4 * 4 + (j & 3);
    unsafeAtomicAdd(&ws[col + (j >> 2) * 128], v);
  }
}

// ---------------------------------------------------------------------------
// Kernel D: out = relu((out - mean) * rsqrt(var+eps) * gamma + beta)
// ---------------------------------------------------------------------------
__global__ __launch_bounds__(256) void norm_kernel(
    float* __restrict__ out, const float* __restrict__ ws,
    const float* __restrict__ gamma, const float* __restrict__ beta,
    int total4, float invN) {
  const int tid = threadIdx.x;
  const int c4 = tid & 31;
  float4 s = ((const float4*)ws)[c4];
  float4 q = ((const float4*)ws)[32 + c4];
  float4 g = ((const float4*)gamma)[c4];
  float4 b = ((const float4*)beta)[c4];
  float m0 = s.x * invN, m1 = s.y * invN, m2 = s.z * invN, m3 = s.w * invN;
  float sc0 = g.x * rsqrtf(q.x * invN - m0 * m0 + EPS);
  float sc1 = g.y * rsqrtf(q.y * invN - m1 * m1 + EPS);
  float sc2 = g.z * rsqrtf(q.z * invN - m2 * m2 + EPS);
  float sc3 = g.w * rsqrtf(q.w * invN - m3 * m3 + EPS);
  float sh0 = b.x - m0 * sc0, sh1 = b.y - m1 * sc1;
  float sh2 = b.z - m2 * sc2, sh3 = b.w - m3 * sc3;
  float4* o4 = (float4*)out;
  for (int idx = blockIdx.x * 256 + tid; idx < total4; idx += gridDim.x * 256) {
    float4 v = o4[idx];
    v.x = fmaxf(v.x * sc0 + sh0, 0.f);
    v.y = fmaxf(v.y * sc1 + sh1, 0.f);
    v.z = fmaxf(v.z * sc2 + sh2, 0.f);
    v.w = fmaxf(v.w * sc3 + sh3, 0.f);
    o4[idx] = v;
  }
}

extern "C" void kernel_launch(void* const* d_in, const int* in_sizes, int n_in,
                              void* d_out, int out_size, void* d_ws, size_t ws_size,
                              hipStream_t stream) {
  const float* f1 = (const float*)d_in[0];
  const float* f2 = (const float*)d_in[1];
  const float* W = (const float*)d_in[2];
  const float* bias = (const float*)d_in[3];
  const float* gamma = (const float*)d_in[4];
  const float* beta = (const float*)d_in[5];
  const int* G = (const int*)d_in[6];
  const int* S = (const int*)d_in[7];
  const int N1 = in_sizes[0] / 64;
  const int N2 = in_sizes[1] / 64;
  const int N = N1 + N2;
  const int pm = in_sizes[6] / 26;
  float* out = (float*)d_out;
  float* ws = (float*)d_ws;

  hipMemsetAsync(ws, 0, 256 * sizeof(float), stream);

  center_gemm<<<(N + 127) / 128, 256, 0, stream>>>(
      f1, f2, W + (size_t)13 * 64 * 128, bias, out, N, N1);

  dim3 gB((pm + 127) / 128, 26);
  msg_gemm<<<gB, 256, 0, stream>>>(f1, f2, W, G, S, out, N, N1, pm);

  const int total4 = (N * 128) / 4;
  stats_kernel<<<1024, 256, 0, stream>>>(out, ws, total4);
  norm_kernel<<<2048, 256, 0, stream>>>(out, ws, gamma, beta, total4, 1.0f / N);
}

// Round 2
// 383.436 us; speedup vs baseline: 2.5645x; 2.5645x over previous
//
#include <hip/hip_runtime.h>

#define EPS 1e-3f

static __device__ __forceinline__ unsigned f2bf_pack(float a, float b) {
  union { float f; unsigned u; } ca, cb;
  ca.f = a; cb.f = b;
  unsigned ra = (ca.u + 0x7FFFu + ((ca.u >> 16) & 1u)) >> 16;
  unsigned rb = (cb.u + 0x7FFFu + ((cb.u >> 16) & 1u)) >> 16;
  return ra | (rb << 16);
}
static __device__ __forceinline__ float bf2f(unsigned bits16) {
  union { unsigned u; float f; } c;
  c.u = bits16 << 16;
  return c.f;
}

// ---------------------------------------------------------------------------
// Kernel A: center-tap GEMM  out[n][col] = feats[n] . W13[:,col] + bias[col]
// ---------------------------------------------------------------------------
__global__ __launch_bounds__(256) void center_gemm(
    const float* __restrict__ f1, const float* __restrict__ f2,
    const float* __restrict__ W, const float* __restrict__ bias,
    float* __restrict__ out, int N, int N1) {
  __shared__ float fLDS[128 * 65];
  __shared__ float wLDS[32 * 128];
  const int tid = threadIdx.x;
  const int tx = tid & 15, ty = tid >> 4;
  const int row0 = blockIdx.x * 128;

  for (int k = 0; k < 8; ++k) {
    int flat4 = tid + k * 256;
    int row = flat4 >> 4, c4 = flat4 & 15;
    int grow = row0 + row;
    float4 v = make_float4(0.f, 0.f, 0.f, 0.f);
    if (grow < N) {
      const float* src = (grow < N1) ? (f1 + (size_t)grow * 64)
                                     : (f2 + (size_t)(grow - N1) * 64);
      v = *(const float4*)(src + c4 * 4);
    }
    int l = row * 65 + c4 * 4;
    fLDS[l + 0] = v.x; fLDS[l + 1] = v.y; fLDS[l + 2] = v.z; fLDS[l + 3] = v.w;
  }

  float acc[8][8];
#pragma unroll
  for (int r = 0; r < 8; ++r)
#pragma unroll
    for (int j = 0; j < 8; ++j) acc[r][j] = 0.f;

  for (int kk = 0; kk < 64; kk += 32) {
    __syncthreads();
    for (int k = 0; k < 4; ++k) {
      int flat4 = tid + k * 256;
      int c = flat4 >> 5, col4 = flat4 & 31;
      float4 v = *(const float4*)(W + (size_t)(kk + c) * 128 + col4 * 4);
      *(float4*)(wLDS + c * 128 + col4 * 4) = v;
    }
    __syncthreads();

#pragma unroll 4
    for (int c = 0; c < 32; ++c) {
      float a[8];
#pragma unroll
      for (int r = 0; r < 8; ++r) a[r] = fLDS[(ty * 8 + r) * 65 + kk + c];
      float4 b0 = *(const float4*)(wLDS + c * 128 + tx * 8);
      float4 b1 = *(const float4*)(wLDS + c * 128 + tx * 8 + 4);
      float b[8] = {b0.x, b0.y, b0.z, b0.w, b1.x, b1.y, b1.z, b1.w};
#pragma unroll
      for (int r = 0; r < 8; ++r)
#pragma unroll
        for (int j = 0; j < 8; ++j) acc[r][j] += a[r] * b[j];
    }
  }

  float4 bi0 = *(const float4*)(bias + tx * 8);
  float4 bi1 = *(const float4*)(bias + tx * 8 + 4);
#pragma unroll
  for (int r = 0; r < 8; ++r) {
    int grow = row0 + ty * 8 + r;
    if (grow < N) {
      float4 o0 = make_float4(acc[r][0] + bi0.x, acc[r][1] + bi0.y,
                              acc[r][2] + bi0.z, acc[r][3] + bi0.w);
      float4 o1 = make_float4(acc[r][4] + bi1.x, acc[r][5] + bi1.y,
                              acc[r][6] + bi1.z, acc[r][7] + bi1.w);
      float* dst = out + (size_t)grow * 128 + tx * 8;
      *(float4*)dst = o0;
      *(float4*)(dst + 4) = o1;
    }
  }
}

// ---------------------------------------------------------------------------
// scatter_R: build inverse rulebook. R[s*26+i] = i*pm+p (msgbuf row index)
// R pre-initialized to -1 via hipMemsetAsync(0xFF).
// ---------------------------------------------------------------------------
__global__ __launch_bounds__(256) void scatter_R(
    const int* __restrict__ S, int* __restrict__ R, int N, int pm) {
  const int p = blockIdx.x * 256 + threadIdx.x;
  const int i = blockIdx.y;
  if (p >= pm) return;
  const int idx = i * pm + p;
  const int s = S[idx];
  if (s < N) R[(size_t)s * 26 + i] = idx;
}

// ---------------------------------------------------------------------------
// Kernel B (fast path): per-tap GEMM, writes bf16 messages to msgbuf
// (coalesced 16B stores, no atomics).
// ---------------------------------------------------------------------------
__global__ __launch_bounds__(256) void msg_gemm_buf(
    const float* __restrict__ f1, const float* __restrict__ f2,
    const float* __restrict__ W27, const int* __restrict__ G,
    const int* __restrict__ S, unsigned short* __restrict__ msgbuf,
    int N, int N1, int pm) {
  const int i = blockIdx.y;
  const int ktap = i + (i >= 13 ? 1 : 0);
  const float* W = W27 + (size_t)ktap * 64 * 128;
  const int* Gi = G + (size_t)i * pm;
  const int* Si = S + (size_t)i * pm;
  const int p0 = blockIdx.x * 128;

  if (Si[p0] >= N) return;  // fully-padded tail block

  __shared__ float fLDS[128 * 65];
  __shared__ float wLDS[32 * 128];
  const int tid = threadIdx.x;
  const int tx = tid & 15, ty = tid >> 4;

  for (int k = 0; k < 8; ++k) {
    int flat4 = tid + k * 256;
    int row = flat4 >> 4, c4 = flat4 & 15;
    int p = p0 + row;
    float4 v = make_float4(0.f, 0.f, 0.f, 0.f);
    if (p < pm) {
      int g = Gi[p];
      if (g < N) {
        const float* src = (g < N1) ? (f1 + (size_t)g * 64)
                                    : (f2 + (size_t)(g - N1) * 64);
        v = *(const float4*)(src + c4 * 4);
      }
    }
    int l = row * 65 + c4 * 4;
    fLDS[l + 0] = v.x; fLDS[l + 1] = v.y; fLDS[l + 2] = v.z; fLDS[l + 3] = v.w;
  }

  float acc[8][8];
#pragma unroll
  for (int r = 0; r < 8; ++r)
#pragma unroll
    for (int j = 0; j < 8; ++j) acc[r][j] = 0.f;

  for (int kk = 0; kk < 64; kk += 32) {
    __syncthreads();
    for (int k = 0; k < 4; ++k) {
      int flat4 = tid + k * 256;
      int c = flat4 >> 5, col4 = flat4 & 31;
      float4 v = *(const float4*)(W + (size_t)(kk + c) * 128 + col4 * 4);
      *(float4*)(wLDS + c * 128 + col4 * 4) = v;
    }
    __syncthreads();

#pragma unroll 4
    for (int c = 0; c < 32; ++c) {
      float a[8];
#pragma unroll
      for (int r = 0; r < 8; ++r) a[r] = fLDS[(ty * 8 + r) * 65 + kk + c];
      float4 b0 = *(const float4*)(wLDS + c * 128 + tx * 8);
      float4 b1 = *(const float4*)(wLDS + c * 128 + tx * 8 + 4);
      float b[8] = {b0.x, b0.y, b0.z, b0.w, b1.x, b1.y, b1.z, b1.w};
#pragma unroll
      for (int r = 0; r < 8; ++r)
#pragma unroll
        for (int j = 0; j < 8; ++j) acc[r][j] += a[r] * b[j];
    }
  }

#pragma unroll
  for (int r = 0; r < 8; ++r) {
    int p = p0 + ty * 8 + r;
    if (p < pm) {
      uint4 pk;
      pk.x = f2bf_pack(acc[r][0], acc[r][1]);
      pk.y = f2bf_pack(acc[r][2], acc[r][3]);
      pk.z = f2bf_pack(acc[r][4], acc[r][5]);
      pk.w = f2bf_pack(acc[r][6], acc[r][7]);
      *(uint4*)(msgbuf + ((size_t)i * pm + p) * 128 + tx * 8) = pk;
    }
  }
}

// ---------------------------------------------------------------------------
// Kernel B (fallback): atomic scatter path (used only if ws too small)
// ---------------------------------------------------------------------------
__global__ __launch_bounds__(256) void msg_gemm(
    const float* __restrict__ f1, const float* __restrict__ f2,
    const float* __restrict__ W27, const int* __restrict__ G,
    const int* __restrict__ S, float* __restrict__ out,
    int N, int N1, int pm) {
  const int i = blockIdx.y;
  const int ktap = i + (i >= 13 ? 1 : 0);
  const float* W = W27 + (size_t)ktap * 64 * 128;
  const int* Gi = G + (size_t)i * pm;
  const int* Si = S + (size_t)i * pm;
  const int p0 = blockIdx.x * 128;
  if (Si[p0] >= N) return;

  __shared__ float fLDS[128 * 65];
  __shared__ float wLDS[32 * 128];
  const int tid = threadIdx.x;
  const int tx = tid & 15, ty = tid >> 4;

  for (int k = 0; k < 8; ++k) {
    int flat4 = tid + k * 256;
    int row = flat4 >> 4, c4 = flat4 & 15;
    int p = p0 + row;
    float4 v = make_float4(0.f, 0.f, 0.f, 0.f);
    if (p < pm) {
      int g = Gi[p];
      if (g < N) {
        const float* src = (g < N1) ? (f1 + (size_t)g * 64)
                                    : (f2 + (size_t)(g - N1) * 64);
        v = *(const float4*)(src + c4 * 4);
      }
    }
    int l = row * 65 + c4 * 4;
    fLDS[l + 0] = v.x; fLDS[l + 1] = v.y; fLDS[l + 2] = v.z; fLDS[l + 3] = v.w;
  }

  float acc[8][8];
#pragma unroll
  for (int r = 0; r < 8; ++r)
#pragma unroll
    for (int j = 0; j < 8; ++j) acc[r][j] = 0.f;

  for (int kk = 0; kk < 64; kk += 32) {
    __syncthreads();
    for (int k = 0; k < 4; ++k) {
      int flat4 = tid + k * 256;
      int c = flat4 >> 5, col4 = flat4 & 31;
      float4 v = *(const float4*)(W + (size_t)(kk + c) * 128 + col4 * 4);
      *(float4*)(wLDS + c * 128 + col4 * 4) = v;
    }
    __syncthreads();
#pragma unroll 4
    for (int c = 0; c < 32; ++c) {
      float a[8];
#pragma unroll
      for (int r = 0; r < 8; ++r) a[r] = fLDS[(ty * 8 + r) * 65 + kk + c];
      float4 b0 = *(const float4*)(wLDS + c * 128 + tx * 8);
      float4 b1 = *(const float4*)(wLDS + c * 128 + tx * 8 + 4);
      float b[8] = {b0.x, b0.y, b0.z, b0.w, b1.x, b1.y, b1.z, b1.w};
#pragma unroll
      for (int r = 0; r < 8; ++r)
#pragma unroll
        for (int j = 0; j < 8; ++j) acc[r][j] += a[r] * b[j];
    }
  }

#pragma unroll
  for (int r = 0; r < 8; ++r) {
    int p = p0 + ty * 8 + r;
    if (p < pm) {
      int s = Si[p];
      if (s < N) {
        float* dst = out + (size_t)s * 128 + tx * 8;
#pragma unroll
        for (int j = 0; j < 8; ++j) unsafeAtomicAdd(dst + j, acc[r][j]);
      }
    }
  }
}

// ---------------------------------------------------------------------------
// combine_stats: out[j] += sum of this row's bf16 messages (via inverse table
// R), and accumulate per-channel sum / sumsq partials into ws[0..255].
// One 32-lane group per row, 8 rows per block-iteration, grid-stride.
// ---------------------------------------------------------------------------
__global__ __launch_bounds__(256) void combine_stats(
    float* __restrict__ out, const int* __restrict__ R,
    const unsigned short* __restrict__ msgbuf, float* __restrict__ ws,
    int N) {
  const int tid = threadIdx.x;
  const int grp = tid >> 5, l = tid & 31;
  const int base = tid & 32;  // lane-group base within the 64-lane wave
  float4 s = make_float4(0.f, 0.f, 0.f, 0.f);
  float4 q = make_float4(0.f, 0.f, 0.f, 0.f);

  for (int j = blockIdx.x * 8 + grp; j < N; j += gridDim.x * 8) {
    float4 v = ((const float4*)(out + (size_t)j * 128))[l];
    int r = (l < 26) ? R[(size_t)j * 26 + l] : -1;
    unsigned long long bal = __ballot(r >= 0);
    unsigned mym = (unsigned)((bal >> base) & 0x3FFFFFFull);
    const bool any = (mym != 0);
    while (mym) {
      int b = __builtin_ctz(mym);
      mym &= mym - 1;
      int ptr = __shfl(r, base + b, 64);
      uint2 mv = ((const uint2*)(msgbuf + (size_t)ptr * 128))[l];
      v.x += bf2f(mv.x & 0xffffu);
      v.y += bf2f(mv.x >> 16);
      v.z += bf2f(mv.y & 0xffffu);
      v.w += bf2f(mv.y >> 16);
    }
    if (any) ((float4*)(out + (size_t)j * 128))[l] = v;
    s.x += v.x; s.y += v.y; s.z += v.z; s.w += v.w;
    q.x += v.x * v.x; q.y += v.y * v.y; q.z += v.z * v.z; q.w += v.w * v.w;
  }

  __shared__ float red[8 * 32 * 8];
  float* my = red + (grp * 32 + l) * 8;
  my[0] = s.x; my[1] = s.y; my[2] = s.z; my[3] = s.w;
  my[4] = q.x; my[5] = q.y; my[6] = q.z; my[7] = q.w;
  __syncthreads();
  {
    int c4 = tid & 31, j = tid >> 5;  // j in 0..7
    float v = 0.f;
#pragma unroll
    for (int g = 0; g < 8; ++g) v += red[(g * 32 + c4) * 8 + j];
    int col = c4 * 4 + (j & 3);
    unsafeAtomicAdd(&ws[col + (j >> 2) * 128], v);
  }
}

// ---------------------------------------------------------------------------
// stats_kernel (fallback path only)
// ---------------------------------------------------------------------------
__global__ __launch_bounds__(256) void stats_kernel(
    const float* __restrict__ out, float* __restrict__ ws, int total4) {
  const int tid = threadIdx.x;
  float4 s = make_float4(0.f, 0.f, 0.f, 0.f);
  float4 q = make_float4(0.f, 0.f, 0.f, 0.f);
  const float4* o4 = (const float4*)out;
  for (int idx = blockIdx.x * 256 + tid; idx < total4; idx += gridDim.x * 256) {
    float4 v = o4[idx];
    s.x += v.x; s.y += v.y; s.z += v.z; s.w += v.w;
    q.x += v.x * v.x; q.y += v.y * v.y; q.z += v.z * v.z; q.w += v.w * v.w;
  }
  __shared__ float red[8 * 32 * 8];
  const int col4 = tid & 31, grpq = tid >> 5;
  float* my = red + (grpq * 32 + col4) * 8;
  my[0] = s.x; my[1] = s.y; my[2] = s.z; my[3] = s.w;
  my[4] = q.x; my[5] = q.y; my[6] = q.z; my[7] = q.w;
  __syncthreads();
  {
    int c4 = tid & 31, j = tid >> 5;
    float v = 0.f;
#pragma unroll
    for (int g = 0; g < 8; ++g) v += red[(g * 32 + c4) * 8 + j];
    int col = c4 * 4 + (j & 3);
    unsafeAtomicAdd(&ws[col + (j >> 2) * 128], v);
  }
}

// ---------------------------------------------------------------------------
// norm_kernel: out = relu((out - mean) * rsqrt(var+eps) * gamma + beta)
// ---------------------------------------------------------------------------
__global__ __launch_bounds__(256) void norm_kernel(
    float* __restrict__ out, const float* __restrict__ ws,
    const float* __restrict__ gamma, const float* __restrict__ beta,
    int total4, float invN) {
  const int tid = threadIdx.x;
  const int c4 = tid & 31;
  float4 s = ((const float4*)ws)[c4];
  float4 q = ((const float4*)ws)[32 + c4];
  float4 g = ((const float4*)gamma)[c4];
  float4 b = ((const float4*)beta)[c4];
  float m0 = s.x * invN, m1 = s.y * invN, m2 = s.z * invN, m3 = s.w * invN;
  float sc0 = g.x * rsqrtf(q.x * invN - m0 * m0 + EPS);
  float sc1 = g.y * rsqrtf(q.y * invN - m1 * m1 + EPS);
  float sc2 = g.z * rsqrtf(q.z * invN - m2 * m2 + EPS);
  float sc3 = g.w * rsqrtf(q.w * invN - m3 * m3 + EPS);
  float sh0 = b.x - m0 * sc0, sh1 = b.y - m1 * sc1;
  float sh2 = b.z - m2 * sc2, sh3 = b.w - m3 * sc3;
  float4* o4 = (float4*)out;
  for (int idx = blockIdx.x * 256 + tid; idx < total4; idx += gridDim.x * 256) {
    float4 v = o4[idx];
    v.x = fmaxf(v.x * sc0 + sh0, 0.f);
    v.y = fmaxf(v.y * sc1 + sh1, 0.f);
    v.z = fmaxf(v.z * sc2 + sh2, 0.f);
    v.w = fmaxf(v.w * sc3 + sh3, 0.f);
    o4[idx] = v;
  }
}

extern "C" void kernel_launch(void* const* d_in, const int* in_sizes, int n_in,
                              void* d_out, int out_size, void* d_ws, size_t ws_size,
                              hipStream_t stream) {
  const float* f1 = (const float*)d_in[0];
  const float* f2 = (const float*)d_in[1];
  const float* W = (const float*)d_in[2];
  const float* bias = (const float*)d_in[3];
  const float* gamma = (const float*)d_in[4];
  const float* beta = (const float*)d_in[5];
  const int* G = (const int*)d_in[6];
  const int* S = (const int*)d_in[7];
  const int N1 = in_sizes[0] / 64;
  const int N2 = in_sizes[1] / 64;
  const int N = N1 + N2;
  const int pm = in_sizes[6] / 26;
  float* out = (float*)d_out;
  float* ws = (float*)d_ws;

  // ws layout: [0,1KB) stats | [1KB, +N*26*4) inverse table R | msgbuf (bf16)
  const size_t Roff = 1024;
  const size_t Rbytes = (size_t)N * 26 * 4;
  const size_t Moff = (Roff + Rbytes + 255) & ~(size_t)255;
  const size_t Mbytes = (size_t)26 * pm * 128 * 2;
  const bool fast = ws_size >= Moff + Mbytes;

  hipMemsetAsync(ws, 0, 256 * sizeof(float), stream);

  center_gemm<<<(N + 127) / 128, 256, 0, stream>>>(
      f1, f2, W + (size_t)13 * 64 * 128, bias, out, N, N1);

  dim3 gB((pm + 127) / 128, 26);
  const int total4 = (N * 128) / 4;

  if (fast) {
    int* R = (int*)((char*)d_ws + Roff);
    unsigned short* msgbuf = (unsigned short*)((char*)d_ws + Moff);
    hipMemsetAsync(R, 0xFF, Rbytes, stream);
    scatter_R<<<dim3((pm + 255) / 256, 26), 256, 0, stream>>>(S, R, N, pm);
    msg_gemm_buf<<<gB, 256, 0, stream>>>(f1, f2, W, G, S, msgbuf, N, N1, pm);
    combine_stats<<<1024, 256, 0, stream>>>(out, R, msgbuf, ws, N);
  } else {
    msg_gemm<<<gB, 256, 0, stream>>>(f1, f2, W, G, S, out, N, N1, pm);
    stats_kernel<<<1024, 256, 0, stream>>>(out, ws, total4);
  }

  norm_kernel<<<2048, 256, 0, stream>>>(out, ws, gamma, beta, total4, 1.0f / N);
}